// Round 8
// baseline (311.555 us; speedup 1.0000x reference)
//
#include <hip/hip_runtime.h>
#include <hip/hip_bf16.h>
#include <math.h>

#define B_  64
#define NS  512
#define NR  256
#define DD  1024
#define NEGV (-1e10f)

typedef __attribute__((ext_vector_type(4))) float f32x4;
typedef __attribute__((ext_vector_type(8))) short bf16x8;

__device__ __forceinline__ unsigned short f2bf(float x) {
    unsigned u = __builtin_bit_cast(unsigned, x);
    unsigned r = u + 0x7FFFu + ((u >> 16) & 1u);
    return (unsigned short)(r >> 16);
}
// packed bf16 convert: D.lo = bf16(x), D.hi = bf16(y)
__device__ __forceinline__ unsigned pk2(float x, float y) {
    unsigned r;
    asm("v_cvt_pk_bf16_f32 %0, %1, %2" : "=v"(r) : "v"(x), "v"(y));
    return r;
}
__device__ __forceinline__ void pk_hilo(float x, float y, unsigned& h, unsigned& l) {
    h = pk2(x, y);
    const float hx = __builtin_bit_cast(float, h << 16);
    const float hy = __builtin_bit_cast(float, h & 0xFFFF0000u);
    l = pk2(x - hx, y - hy);
}
// async global->LDS, 16B per lane
__device__ __forceinline__ void gload16(const void* g, void* l) {
    __builtin_amdgcn_global_load_lds((const __attribute__((address_space(1))) void*)g,
                                     (__attribute__((address_space(3))) void*)l, 16, 0, 0);
}

// ---------------------------------------------------------------- zero ws
__global__ __launch_bounds__(64) void zero_ws(double* ws) {
    if (threadIdx.x == 0) { ws[0] = 0.0; ws[1] = 0.0; }
}

// ================================================================ stage 1 (unchanged from r7: 110us local optimum)
__global__ __launch_bounds__(256) void att_mfma(
    const float* __restrict__ span, const float* __restrict__ image,
    const int* __restrict__ smask, const int* __restrict__ imask,
    float* __restrict__ att, float* __restrict__ rowP, float* __restrict__ colP,
    int doStats) {
    const int b  = blockIdx.z;
    const int s0 = blockIdx.y * 128;
    const int r0 = blockIdx.x * 128;
    __shared__ unsigned short Ah[128][40], Al[128][40], Bh[128][40], Bl[128][40];
    const int tid  = threadIdx.x;
    const int lane = tid & 63;
    const int w    = tid >> 6;
    const int wso  = (w >> 1) * 64;
    const int wro  = (w & 1) * 64;
    const float* Sp = span  + ((size_t)b * NS + s0) * DD;
    const float* Im = image + ((size_t)b * NR + r0) * DD;

    f32x4 acc[4][4];
    #pragma unroll
    for (int i = 0; i < 4; ++i)
        #pragma unroll
        for (int j = 0; j < 4; ++j) acc[i][j] = (f32x4){0.f, 0.f, 0.f, 0.f};

    const int krel = (tid & 7) * 4;   // 0..28
    const int row0 = tid >> 3;        // 0..31
    const int fr   = lane & 15;
    const int fk   = (lane >> 4) * 8;

    for (int k0 = 0; k0 < DD; k0 += 32) {
        #pragma unroll
        for (int p = 0; p < 4; ++p) {
            const int row = row0 + p * 32;
            const float4 a = *reinterpret_cast<const float4*>(Sp + (size_t)row * DD + k0 + krel);
            const float4 c = *reinterpret_cast<const float4*>(Im + (size_t)row * DD + k0 + krel);
            unsigned h0, l0, h1, l1;
            uint2 u;
            pk_hilo(a.x, a.y, h0, l0); pk_hilo(a.z, a.w, h1, l1);
            u.x = h0; u.y = h1; *reinterpret_cast<uint2*>(&Ah[row][krel]) = u;
            u.x = l0; u.y = l1; *reinterpret_cast<uint2*>(&Al[row][krel]) = u;
            pk_hilo(c.x, c.y, h0, l0); pk_hilo(c.z, c.w, h1, l1);
            u.x = h0; u.y = h1; *reinterpret_cast<uint2*>(&Bh[row][krel]) = u;
            u.x = l0; u.y = l1; *reinterpret_cast<uint2*>(&Bl[row][krel]) = u;
        }
        __syncthreads();
        bf16x8 ah[4], al[4], bh[4], bl[4];
        #pragma unroll
        for (int mf = 0; mf < 4; ++mf) {
            ah[mf] = *reinterpret_cast<const bf16x8*>(&Ah[wso + mf * 16 + fr][fk]);
            al[mf] = *reinterpret_cast<const bf16x8*>(&Al[wso + mf * 16 + fr][fk]);
            bh[mf] = *reinterpret_cast<const bf16x8*>(&Bh[wro + mf * 16 + fr][fk]);
            bl[mf] = *reinterpret_cast<const bf16x8*>(&Bl[wro + mf * 16 + fr][fk]);
        }
        #pragma unroll
        for (int mf = 0; mf < 4; ++mf)
            #pragma unroll
            for (int nf = 0; nf < 4; ++nf) {
                acc[mf][nf] = __builtin_amdgcn_mfma_f32_16x16x32_bf16(ah[mf], bh[nf], acc[mf][nf], 0, 0, 0);
                acc[mf][nf] = __builtin_amdgcn_mfma_f32_16x16x32_bf16(ah[mf], bl[nf], acc[mf][nf], 0, 0, 0);
                acc[mf][nf] = __builtin_amdgcn_mfma_f32_16x16x32_bf16(al[mf], bh[nf], acc[mf][nf], 0, 0, 0);
            }
        __syncthreads();
    }

    // ---- epilogue: mask + zero->NEG store, max-only fused stats
    float* rowLDS = reinterpret_cast<float*>(&Ah[0][0]);   // [128][2] aliased on dead staging
    float* colLDS = rowLDS + 256;                          // [128][2]
    const int fq = lane >> 4;
    int imv[4];
    #pragma unroll
    for (int nf = 0; nf < 4; ++nf) imv[nf] = imask[b * NR + r0 + wro + nf * 16 + fr];
    float cmax[4] = {-3.4e38f, -3.4e38f, -3.4e38f, -3.4e38f};
    #pragma unroll
    for (int mf = 0; mf < 4; ++mf) {
        #pragma unroll
        for (int i = 0; i < 4; ++i) {
            const int s = s0 + wso + mf * 16 + fq * 4 + i;
            const int sm = smask[b * NS + s];
            float* orow = att + ((size_t)b * NS + s) * NR + r0 + wro;
            float vj[4];
            #pragma unroll
            for (int nf = 0; nf < 4; ++nf) {
                float v = acc[mf][nf][i] * (float)(sm * imv[nf]);
                v = (v != 0.0f) ? v : NEGV;
                orow[nf * 16 + fr] = v;
                vj[nf] = v;
                cmax[nf] = fmaxf(cmax[nf], v);
            }
            if (doStats) {
                float rm = fmaxf(fmaxf(vj[0], vj[1]), fmaxf(vj[2], vj[3]));
                rm = fmaxf(rm, __shfl_xor(rm, 1));
                rm = fmaxf(rm, __shfl_xor(rm, 2));
                rm = fmaxf(rm, __shfl_xor(rm, 4));
                rm = fmaxf(rm, __shfl_xor(rm, 8));
                if (fr == 0) rowLDS[(wso + mf * 16 + fq * 4 + i) * 2 + (w & 1)] = rm;
            }
        }
    }
    if (doStats) {
        #pragma unroll
        for (int nf = 0; nf < 4; ++nf) {
            cmax[nf] = fmaxf(cmax[nf], __shfl_xor(cmax[nf], 16));
            cmax[nf] = fmaxf(cmax[nf], __shfl_xor(cmax[nf], 32));
        }
        if (lane < 16) {
            #pragma unroll
            for (int nf = 0; nf < 4; ++nf)
                colLDS[(wro + nf * 16 + lane) * 2 + (w >> 1)] = cmax[nf];
        }
        __syncthreads();
        if (tid < 128) {
            rowP[((size_t)b * NS + s0 + tid) * 2 + blockIdx.x] =
                fmaxf(rowLDS[tid * 2 + 0], rowLDS[tid * 2 + 1]);
        } else {
            const int c = tid - 128;
            colP[((size_t)b * NR + r0 + c) * 4 + blockIdx.y] =
                fmaxf(colLDS[c * 2 + 0], colLDS[c * 2 + 1]);
        }
    }
}

// ================================================================ combine partial maxes -> m1 (rows), m2 (cols)
__global__ __launch_bounds__(256) void combine_max(
    const float* __restrict__ rowP, const float* __restrict__ colP,
    float* __restrict__ m1, float* __restrict__ m2) {
    const int idx = blockIdx.x * 256 + threadIdx.x;
    if (idx < B_ * NS) {
        m1[idx] = fmaxf(rowP[(size_t)idx * 2 + 0], rowP[(size_t)idx * 2 + 1]);
    } else if (idx < B_ * NS + B_ * NR) {
        const int j = idx - B_ * NS;
        m2[j] = fmaxf(fmaxf(colP[(size_t)j * 4 + 0], colP[(size_t)j * 4 + 1]),
                      fmaxf(colP[(size_t)j * 4 + 2], colP[(size_t)j * 4 + 3]));
    }
}

// ================================================================ transpose f32 -> bf16, K-swizzled within 64-chunks by (d&7)<<3
__global__ __launch_bounds__(256) void transpose_swz(
    const float* __restrict__ src, unsigned short* __restrict__ dst, int N) {
    const int b = blockIdx.z, n0 = blockIdx.y * 32, d0 = blockIdx.x * 32;
    __shared__ unsigned short T[32][36];
    const int t = threadIdx.x;
    {
        const int n = t >> 3, dq = (t & 7) * 4;
        const float4 v = *reinterpret_cast<const float4*>(src + ((size_t)b * N + n0 + n) * DD + d0 + dq);
        T[dq + 0][n] = f2bf(v.x); T[dq + 1][n] = f2bf(v.y);
        T[dq + 2][n] = f2bf(v.z); T[dq + 3][n] = f2bf(v.w);
    }
    __syncthreads();
    {
        const int d = t >> 3, nq = (t & 7) * 4;
        const int dg = d0 + d;
        const int base = n0 + nq;
        const int pos = (base & 63) ^ ((dg & 7) << 3);
        const size_t idx = ((size_t)b * DD + dg) * N + (base & ~63) + pos;
        *reinterpret_cast<ushort4*>(dst + idx) = *reinterpret_cast<const ushort4*>(&T[d][nq]);
    }
}

// ================================================================ gemm1 fused: att_first[s][d] = softmax-row(att) @ image
// A (w1) computed in staging from att f32; rowsum in-block; norm in epilogue.
__global__ __launch_bounds__(256) void gemm1_fused(
    const float* __restrict__ att, const unsigned short* __restrict__ imgT,
    const float* __restrict__ span,
    const int* __restrict__ smask, const int* __restrict__ imask,
    const float* __restrict__ m1,
    float* __restrict__ att_first, double* __restrict__ wsum) {
    const int b = blockIdx.z, m0 = blockIdx.y * 64, d0 = blockIdx.x * 256;
    __shared__ unsigned short As[64 * 64];
    __shared__ unsigned short Bs[256 * 64];
    __shared__ float redsum[256];
    __shared__ float m1s[64], sms[64], rowsumS[64];
    __shared__ float ims[256];
    const int tid = threadIdx.x, lane = tid & 63, w = tid >> 6;
    const int fr = lane & 15, fq = lane >> 4;
    if (tid < 64) {
        m1s[tid] = m1[b * NS + m0 + tid];
        sms[tid] = (float)smask[b * NS + m0 + tid];
    }
    ims[tid] = (float)imask[b * NR + tid];
    f32x4 acc[4][4];
    #pragma unroll
    for (int i = 0; i < 4; ++i)
        #pragma unroll
        for (int j = 0; j < 4; ++j) acc[i][j] = (f32x4){0.f, 0.f, 0.f, 0.f};

    const int arow = tid >> 2;           // staged A row 0..63
    const int acg  = (tid & 3) * 16;     // col group (16 shorts)
    const int akey = (arow & 7) << 3;
    const int srow = tid >> 3;           // B staging row
    const int scol = (tid & 7) * 16;     // B byte offset in 128B chunk
    float rsum = 0.0f;
    __syncthreads();

    for (int kc = 0; kc < NR / 64; ++kc) {
        // ---- B: imgT bf16, pre-swizzled, async global->LDS
        const char* bsrc = (const char*)(imgT + ((size_t)b * DD + d0) * NR) + kc * 128 + scol;
        #pragma unroll
        for (int c = 0; c < 8; ++c)
            gload16(bsrc + (size_t)(c * 32 + srow) * (NR * 2), (char*)Bs + (c * 256 + tid) * 16);
        // ---- A: att f32 -> exp -> bf16 -> swizzled LDS; accumulate rowsum
        {
            const float* ap = att + ((size_t)b * NS + m0 + arow) * NR + kc * 64 + acg;
            const float m1v = m1s[arow];
            const float4 a0 = *reinterpret_cast<const float4*>(ap);
            const float4 a1 = *reinterpret_cast<const float4*>(ap + 4);
            const float4 a2 = *reinterpret_cast<const float4*>(ap + 8);
            const float4 a3 = *reinterpret_cast<const float4*>(ap + 12);
            float e[16];
            e[0] = __expf(a0.x - m1v); e[1] = __expf(a0.y - m1v);
            e[2] = __expf(a0.z - m1v); e[3] = __expf(a0.w - m1v);
            e[4] = __expf(a1.x - m1v); e[5] = __expf(a1.y - m1v);
            e[6] = __expf(a1.z - m1v); e[7] = __expf(a1.w - m1v);
            e[8] = __expf(a2.x - m1v); e[9] = __expf(a2.y - m1v);
            e[10] = __expf(a2.z - m1v); e[11] = __expf(a2.w - m1v);
            e[12] = __expf(a3.x - m1v); e[13] = __expf(a3.y - m1v);
            e[14] = __expf(a3.z - m1v); e[15] = __expf(a3.w - m1v);
            #pragma unroll
            for (int j = 0; j < 16; ++j) rsum += e[j];
            const int ib = kc * 64 + acg;
            uint4 u;
            u.x = pk2(e[0] * ims[ib + 0], e[1] * ims[ib + 1]);
            u.y = pk2(e[2] * ims[ib + 2], e[3] * ims[ib + 3]);
            u.z = pk2(e[4] * ims[ib + 4], e[5] * ims[ib + 5]);
            u.w = pk2(e[6] * ims[ib + 6], e[7] * ims[ib + 7]);
            *reinterpret_cast<uint4*>(&As[arow * 64 + (acg ^ akey)]) = u;
            u.x = pk2(e[8] * ims[ib + 8], e[9] * ims[ib + 9]);
            u.y = pk2(e[10] * ims[ib + 10], e[11] * ims[ib + 11]);
            u.z = pk2(e[12] * ims[ib + 12], e[13] * ims[ib + 13]);
            u.w = pk2(e[14] * ims[ib + 14], e[15] * ims[ib + 15]);
            *reinterpret_cast<uint4*>(&As[arow * 64 + ((acg + 8) ^ akey)]) = u;
        }
        __syncthreads();
        #pragma unroll
        for (int ks = 0; ks < 2; ++ks) {
            bf16x8 aF[4], bF[4];
            #pragma unroll
            for (int mf = 0; mf < 4; ++mf) {
                const int row = mf * 16 + fr;
                const int pos = (ks * 32 + fq * 8) ^ ((row & 7) << 3);
                aF[mf] = *reinterpret_cast<const bf16x8*>(&As[row * 64 + pos]);
            }
            #pragma unroll
            for (int nf = 0; nf < 4; ++nf) {
                const int row = w * 64 + nf * 16 + fr;
                const int pos = (ks * 32 + fq * 8) ^ ((row & 7) << 3);
                bF[nf] = *reinterpret_cast<const bf16x8*>(&Bs[row * 64 + pos]);
            }
            #pragma unroll
            for (int mf = 0; mf < 4; ++mf)
                #pragma unroll
                for (int nf = 0; nf < 4; ++nf)
                    acc[mf][nf] = __builtin_amdgcn_mfma_f32_16x16x32_bf16(aF[mf], bF[nf], acc[mf][nf], 0, 0, 0);
        }
        __syncthreads();
    }
    // rowsum: 4 threads (tid&3) per row, same wave
    rsum += __shfl_xor(rsum, 1);
    rsum += __shfl_xor(rsum, 2);
    if ((tid & 3) == 0) rowsumS[arow] = rsum;
    __syncthreads();

    float sumsq = 0.0f;
    #pragma unroll
    for (int mf = 0; mf < 4; ++mf) {
        #pragma unroll
        for (int i = 0; i < 4; ++i) {
            const int row = mf * 16 + fq * 4 + i;
            const float fac = sms[row] / rowsumS[row];
            const size_t base = ((size_t)b * NS + m0 + row) * DD + d0 + w * 64;
            #pragma unroll
            for (int nf = 0; nf < 4; ++nf) {
                const float v = acc[mf][nf][i] * fac;
                const float rv = span[base + nf * 16 + fr];
                att_first[base + nf * 16 + fr] = v;
                const float dx = rv - v;
                sumsq += dx * dx;
            }
        }
    }
    redsum[tid] = sumsq; __syncthreads();
    for (int off = 128; off; off >>= 1) {
        if (tid < off) redsum[tid] += redsum[tid + off];
        __syncthreads();
    }
    if (tid == 0) atomicAdd(wsum, (double)redsum[0]);
}

// ================================================================ gemm2 fused: att_second[r][d] = softmax-col(att)^T @ span (MSE only)
// A (w2) computed in staging: att tile transposed + exp; colsum in-block.
__global__ __launch_bounds__(256) void gemm2_fused(
    const float* __restrict__ att, const unsigned short* __restrict__ spT,
    const float* __restrict__ image,
    const int* __restrict__ smask, const int* __restrict__ imask,
    const float* __restrict__ m2, double* __restrict__ wsum) {
    const int b = blockIdx.z, r0 = blockIdx.y * 64, d0 = blockIdx.x * 256;
    __shared__ unsigned short As[64 * 64];
    __shared__ unsigned short Bs[256 * 64];
    __shared__ float redsum[256];
    __shared__ float m2s[64], imsv[64], colsumS[64];
    __shared__ float smsK[512];
    __shared__ float cs4[4][64];
    const int tid = threadIdx.x, lane = tid & 63, w = tid >> 6;
    const int fr = lane & 15, fq = lane >> 4;
    if (tid < 64) {
        m2s[tid] = m2[b * NR + r0 + tid];
        imsv[tid] = (float)imask[b * NR + r0 + tid];
    }
    smsK[tid]       = (float)smask[b * NS + tid];
    smsK[tid + 256] = (float)smask[b * NS + 256 + tid];
    f32x4 acc[4][4];
    #pragma unroll
    for (int i = 0; i < 4; ++i)
        #pragma unroll
        for (int j = 0; j < 4; ++j) acc[i][j] = (f32x4){0.f, 0.f, 0.f, 0.f};

    const int asr = tid >> 2;            // staged att s-row within kc (0..63)
    const int arg = (tid & 3) * 16;      // r group (16 rows of A)
    const int srow = tid >> 3;
    const int scol = (tid & 7) * 16;
    float csum[16];
    #pragma unroll
    for (int j = 0; j < 16; ++j) csum[j] = 0.0f;
    __syncthreads();

    for (int kc = 0; kc < NS / 64; ++kc) {
        // ---- B: spT bf16, pre-swizzled, async global->LDS
        const char* bsrc = (const char*)(spT + ((size_t)b * DD + d0) * NS) + kc * 128 + scol;
        #pragma unroll
        for (int c = 0; c < 8; ++c)
            gload16(bsrc + (size_t)(c * 32 + srow) * (NS * 2), (char*)Bs + (c * 256 + tid) * 16);
        // ---- A: att f32 [s][r] tile -> transpose + exp -> swizzled LDS [r][s]
        {
            const float* ap = att + ((size_t)b * NS + kc * 64 + asr) * NR + r0 + arg;
            const float smv = smsK[kc * 64 + asr];
            const float4 a0 = *reinterpret_cast<const float4*>(ap);
            const float4 a1 = *reinterpret_cast<const float4*>(ap + 4);
            const float4 a2 = *reinterpret_cast<const float4*>(ap + 8);
            const float4 a3 = *reinterpret_cast<const float4*>(ap + 12);
            const float av[16] = {a0.x, a0.y, a0.z, a0.w, a1.x, a1.y, a1.z, a1.w,
                                  a2.x, a2.y, a2.z, a2.w, a3.x, a3.y, a3.z, a3.w};
            const int slo = asr & 7;
            const int shi = asr >> 3;
            #pragma unroll
            for (int j = 0; j < 16; ++j) {
                const int r = arg + j;
                const float e = __expf(av[j] - m2s[r]);
                csum[j] += e;
                const int pos = slo | ((shi ^ (r & 7)) << 3);
                As[r * 64 + pos] = f2bf(e * smv);
            }
        }
        __syncthreads();
        #pragma unroll
        for (int ks = 0; ks < 2; ++ks) {
            bf16x8 aF[4], bF[4];
            #pragma unroll
            for (int mf = 0; mf < 4; ++mf) {
                const int row = mf * 16 + fr;
                const int pos = (ks * 32 + fq * 8) ^ ((row & 7) << 3);
                aF[mf] = *reinterpret_cast<const bf16x8*>(&As[row * 64 + pos]);
            }
            #pragma unroll
            for (int nf = 0; nf < 4; ++nf) {
                const int row = w * 64 + nf * 16 + fr;
                const int pos = (ks * 32 + fq * 8) ^ ((row & 7) << 3);
                bF[nf] = *reinterpret_cast<const bf16x8*>(&Bs[row * 64 + pos]);
            }
            #pragma unroll
            for (int mf = 0; mf < 4; ++mf)
                #pragma unroll
                for (int nf = 0; nf < 4; ++nf)
                    acc[mf][nf] = __builtin_amdgcn_mfma_f32_16x16x32_bf16(aF[mf], bF[nf], acc[mf][nf], 0, 0, 0);
        }
        __syncthreads();
    }
    // colsum reduce: lanes differing in bits 2..5 share (wave, tid&3)
    #pragma unroll
    for (int j = 0; j < 16; ++j) {
        float v = csum[j];
        v += __shfl_xor(v, 4);
        v += __shfl_xor(v, 8);
        v += __shfl_xor(v, 16);
        v += __shfl_xor(v, 32);
        if (lane < 4) cs4[w][lane * 16 + j] = v;
    }
    __syncthreads();
    if (tid < 64) colsumS[tid] = (cs4[0][tid] + cs4[1][tid]) + (cs4[2][tid] + cs4[3][tid]);
    __syncthreads();

    float sumsq = 0.0f;
    #pragma unroll
    for (int mf = 0; mf < 4; ++mf) {
        #pragma unroll
        for (int i = 0; i < 4; ++i) {
            const int row = mf * 16 + fq * 4 + i;
            const float fac = imsv[row] / colsumS[row];
            const size_t base = ((size_t)b * NR + r0 + row) * DD + d0 + w * 64;
            #pragma unroll
            for (int nf = 0; nf < 4; ++nf) {
                const float dx = image[base + nf * 16 + fr] - acc[mf][nf][i] * fac;
                sumsq += dx * dx;
            }
        }
    }
    redsum[tid] = sumsq; __syncthreads();
    for (int off = 128; off; off >>= 1) {
        if (tid < off) redsum[tid] += redsum[tid + off];
        __syncthreads();
    }
    if (tid == 0) atomicAdd(wsum + 1, (double)redsum[0]);
}

// ================================================================ fallback f32 kernels (used when ws too small)
__global__ __launch_bounds__(256) void first_kernel(
    const float* __restrict__ span, const float* __restrict__ image,
    const int* __restrict__ smask, const int* __restrict__ imask,
    const float* __restrict__ att, float* __restrict__ att_first,
    double* __restrict__ ws) {
    const int b  = blockIdx.y;
    const int s0 = blockIdx.x * 32;
    __shared__ float wT[256][36];
    __shared__ float Is[32][132];
    __shared__ float red[256];
    const int tid  = threadIdx.x;
    const int lane = tid & 63, wave = tid >> 6;
    for (int i = 0; i < 8; ++i) {
        const int srel = wave * 8 + i;
        const int s    = s0 + srel;
        const float4 v = *reinterpret_cast<const float4*>(att + ((size_t)b * NS + s) * NR + lane * 4);
        float m = fmaxf(fmaxf(v.x, v.y), fmaxf(v.z, v.w));
        #pragma unroll
        for (int off = 32; off; off >>= 1) m = fmaxf(m, __shfl_xor(m, off));
        float4 e;
        e.x = expf(v.x - m); e.y = expf(v.y - m); e.z = expf(v.z - m); e.w = expf(v.w - m);
        float sum = e.x + e.y + e.z + e.w;
        #pragma unroll
        for (int off = 32; off; off >>= 1) sum += __shfl_xor(sum, off);
        const float fac = (float)smask[b * NS + s] / sum;
        const int4 im4 = *reinterpret_cast<const int4*>(imask + b * NR + lane * 4);
        wT[lane * 4 + 0][srel] = e.x * fac * (float)im4.x;
        wT[lane * 4 + 1][srel] = e.y * fac * (float)im4.y;
        wT[lane * 4 + 2][srel] = e.z * fac * (float)im4.z;
        wT[lane * 4 + 3][srel] = e.w * fac * (float)im4.w;
    }
    __syncthreads();
    float sumsq = 0.0f;
    const int txd = tid & 31;
    const int tys = tid >> 5;
    const float* Ib = image + (size_t)b * NR * DD;
    for (int dc = 0; dc < 8; ++dc) {
        const int d0 = dc * 128;
        float acc[4][4] = {};
        for (int rc = 0; rc < 8; ++rc) {
            const int r0 = rc * 32;
            {
                const int rr = tid >> 3;
                const int cb = tid & 7;
                const float* src = Ib + (size_t)(r0 + rr) * DD + d0;
                #pragma unroll
                for (int q = 0; q < 4; ++q)
                    *reinterpret_cast<float4*>(&Is[rr][(cb + 8 * q) * 4]) =
                        *reinterpret_cast<const float4*>(src + (cb + 8 * q) * 4);
            }
            __syncthreads();
            #pragma unroll 4
            for (int rr = 0; rr < 32; ++rr) {
                const float4 wv = *reinterpret_cast<const float4*>(&wT[r0 + rr][tys * 4]);
                const float4 iv = *reinterpret_cast<const float4*>(&Is[rr][txd * 4]);
                const float wvv[4] = {wv.x, wv.y, wv.z, wv.w};
                const float ivv[4] = {iv.x, iv.y, iv.z, iv.w};
                #pragma unroll
                for (int i = 0; i < 4; ++i)
                    #pragma unroll
                    for (int j = 0; j < 4; ++j)
                        acc[i][j] += wvv[i] * ivv[j];
            }
            __syncthreads();
        }
        #pragma unroll
        for (int i = 0; i < 4; ++i) {
            const int s = s0 + tys * 4 + i;
            const size_t base = ((size_t)b * NS + s) * DD + d0 + txd * 4;
            const float4 af = {acc[i][0], acc[i][1], acc[i][2], acc[i][3]};
            *reinterpret_cast<float4*>(att_first + base) = af;
            const float4 sp = *reinterpret_cast<const float4*>(span + base);
            float dx;
            dx = sp.x - af.x; sumsq += dx * dx;
            dx = sp.y - af.y; sumsq += dx * dx;
            dx = sp.z - af.z; sumsq += dx * dx;
            dx = sp.w - af.w; sumsq += dx * dx;
        }
    }
    red[tid] = sumsq; __syncthreads();
    for (int off = 128; off; off >>= 1) {
        if (tid < off) red[tid] += red[tid + off];
        __syncthreads();
    }
    if (tid == 0) atomicAdd(ws, (double)red[0]);
}

__global__ __launch_bounds__(256) void second_kernel(
    const float* __restrict__ span, const float* __restrict__ image,
    const int* __restrict__ smask, const int* __restrict__ imask,
    const float* __restrict__ att, double* __restrict__ ws) {
    const int b  = blockIdx.y;
    const int r0 = blockIdx.x * 32;
    __shared__ float w2s[32][36];
    __shared__ float Ss[32][132];
    __shared__ float mArr[32], fArr[32];
    __shared__ float redm[8][32];
    __shared__ float red[256];
    const int tid = threadIdx.x;
    const int rr = tid & 31, q = tid >> 5;
    const float* attb = att + (size_t)b * NS * NR + r0 + rr;
    float mloc = -3.4e38f;
    for (int t = 0; t < 64; ++t)
        mloc = fmaxf(mloc, attb[(size_t)(q * 64 + t) * NR]);
    redm[q][rr] = mloc;
    __syncthreads();
    if (tid < 32) {
        float m = redm[0][tid];
        #pragma unroll
        for (int qq = 1; qq < 8; ++qq) m = fmaxf(m, redm[qq][tid]);
        mArr[tid] = m;
    }
    __syncthreads();
    const float mcol = mArr[rr];
    float sloc = 0.0f;
    for (int t = 0; t < 64; ++t)
        sloc += expf(attb[(size_t)(q * 64 + t) * NR] - mcol);
    redm[q][rr] = sloc;
    __syncthreads();
    if (tid < 32) {
        float s = 0.0f;
        #pragma unroll
        for (int qq = 0; qq < 8; ++qq) s += redm[qq][tid];
        fArr[tid] = (float)imask[b * NR + r0 + tid] / s;
    }
    __syncthreads();
    float sumsq = 0.0f;
    const int txd = tid & 31;
    const int tyr = tid >> 5;
    const float* Sb = span + (size_t)b * NS * DD;
    for (int dc = 0; dc < 8; ++dc) {
        const int d0 = dc * 128;
        float acc[4][4] = {};
        for (int sc = 0; sc < 16; ++sc) {
            const int sb0 = sc * 32;
            {
                const int sr = tid >> 3;
                const int cb = tid & 7;
                const float* src = Sb + (size_t)(sb0 + sr) * DD + d0;
                #pragma unroll
                for (int qq = 0; qq < 4; ++qq)
                    *reinterpret_cast<float4*>(&Ss[sr][(cb + 8 * qq) * 4]) =
                        *reinterpret_cast<const float4*>(src + (cb + 8 * qq) * 4);
            }
            {
                const int ss = tid >> 3;
                const int rq = (tid & 7) * 4;
                const int s  = sb0 + ss;
                const float4 v = *reinterpret_cast<const float4*>(att + ((size_t)b * NS + s) * NR + r0 + rq);
                const float smv = (float)smask[b * NS + s];
                float4 wv;
                wv.x = expf(v.x - mArr[rq + 0]) * fArr[rq + 0] * smv;
                wv.y = expf(v.y - mArr[rq + 1]) * fArr[rq + 1] * smv;
                wv.z = expf(v.z - mArr[rq + 2]) * fArr[rq + 2] * smv;
                wv.w = expf(v.w - mArr[rq + 3]) * fArr[rq + 3] * smv;
                *reinterpret_cast<float4*>(&w2s[ss][rq]) = wv;
            }
            __syncthreads();
            #pragma unroll 4
            for (int ss = 0; ss < 32; ++ss) {
                const float4 wv = *reinterpret_cast<const float4*>(&w2s[ss][tyr * 4]);
                const float4 sv = *reinterpret_cast<const float4*>(&Ss[ss][txd * 4]);
                const float wvv[4] = {wv.x, wv.y, wv.z, wv.w};
                const float svv[4] = {sv.x, sv.y, sv.z, sv.w};
                #pragma unroll
                for (int i = 0; i < 4; ++i)
                    #pragma unroll
                    for (int j = 0; j < 4; ++j)
                        acc[i][j] += wvv[i] * svv[j];
            }
            __syncthreads();
        }
        #pragma unroll
        for (int i = 0; i < 4; ++i) {
            const int r = r0 + tyr * 4 + i;
            const float4 iv = *reinterpret_cast<const float4*>(image + ((size_t)b * NR + r) * DD + d0 + txd * 4);
            float dx;
            dx = iv.x - acc[i][0]; sumsq += dx * dx;
            dx = iv.y - acc[i][1]; sumsq += dx * dx;
            dx = iv.z - acc[i][2]; sumsq += dx * dx;
            dx = iv.w - acc[i][3]; sumsq += dx * dx;
        }
    }
    red[tid] = sumsq; __syncthreads();
    for (int off = 128; off; off >>= 1) {
        if (tid < off) red[tid] += red[tid + off];
        __syncthreads();
    }
    if (tid == 0) atomicAdd(ws + 1, (double)red[0]);
}

// ---------------------------------------------------------------- final score
__global__ __launch_bounds__(64) void score_kernel(const double* __restrict__ ws, float* __restrict__ out) {
    if (threadIdx.x == 0) {
        out[0] = (float)(ws[0] / (double)((size_t)B_ * NS * DD) +
                         ws[1] / (double)((size_t)B_ * NR * DD));
    }
}

extern "C" void kernel_launch(void* const* d_in, const int* in_sizes, int n_in,
                              void* d_out, int out_size, void* d_ws, size_t ws_size,
                              hipStream_t stream) {
    const float* span  = (const float*)d_in[0];
    const float* image = (const float*)d_in[1];
    const int*   smask = (const int*)d_in[2];
    const int*   imask = (const int*)d_in[3];
    float* out       = (float*)d_out;
    float* att_first = out + 1;
    float* att       = out + 1 + (size_t)B_ * NS * DD;

    // ws layout:
    //  wsum(512B) | m1 (B*NS) | m2 (B*NR) | rowP (B*NS*2) | colP (B*NR*4)  (f32)
    //  | X0: imgT (33.5M) for gemm1, then spT (67.1M) overwrites for gemm2
    char* base = (char*)d_ws;
    double* wsum = (double*)base;
    float* m1   = (float*)(base + 512);
    float* m2   = m1 + (size_t)B_ * NS;
    float* rowP = m2 + (size_t)B_ * NR;
    float* colP = rowP + (size_t)B_ * NS * 2;
    char* X0 = (char*)(colP + (size_t)B_ * NR * 4);
    unsigned short* imgT = (unsigned short*)X0;
    unsigned short* spT  = (unsigned short*)X0;
    const size_t NEED = (size_t)(X0 - base) + (size_t)B_ * DD * NS * 2;
    const int wsok = (ws_size >= NEED) ? 1 : 0;

    zero_ws<<<dim3(1), dim3(64), 0, stream>>>(wsum);
    att_mfma<<<dim3(NR / 128, NS / 128, B_), dim3(256), 0, stream>>>(
        span, image, smask, imask, att, rowP, colP, wsok);

    if (wsok) {
        combine_max<<<dim3((B_ * NS + B_ * NR) / 256), dim3(256), 0, stream>>>(
            rowP, colP, m1, m2);
        transpose_swz<<<dim3(DD / 32, NR / 32, B_), dim3(256), 0, stream>>>(image, imgT, NR);
        gemm1_fused<<<dim3(DD / 256, NS / 64, B_), dim3(256), 0, stream>>>(
            att, imgT, span, smask, imask, m1, att_first, wsum);
        transpose_swz<<<dim3(DD / 32, NS / 32, B_), dim3(256), 0, stream>>>(span, spT, NS);
        gemm2_fused<<<dim3(DD / 256, NR / 64, B_), dim3(256), 0, stream>>>(
            att, spT, image, smask, imask, m2, wsum);
    } else {
        first_kernel<<<dim3(NS / 32, B_), dim3(256), 0, stream>>>(span, image, smask, imask, att, att_first, wsum);
        second_kernel<<<dim3(NR / 32, B_), dim3(256), 0, stream>>>(span, image, smask, imask, att, wsum);
    }
    score_kernel<<<dim3(1), dim3(64), 0, stream>>>(wsum, out);
}